// Round 16
// baseline (253.943 us; speedup 1.0000x reference)
//
#include <hip/hip_runtime.h>
#include <hip/hip_bf16.h>

// Problem constants (fixed by setup_inputs)
#define NB 16     // batch
#define CC 64     // channels
#define TT 64
#define VV 25
#define LL 1600   // T*V
#define HH 4
#define DD 64
#define NH 64     // N*H

// Dtype contract (rounds 0-3): d_in fp32, d_out fp32, tolerance bf16-grade.
// Lessons: largest-K MFMA shapes only (r13); block supply != residency (r14);
// 1-wave blocks pack ~2x better than 2-wave blocks on this chip (r5-7 vs r8+).

typedef __hip_bfloat16 bf16;
typedef __attribute__((ext_vector_type(8))) short short8;
typedef __attribute__((ext_vector_type(4))) float f32x4;
typedef __attribute__((ext_vector_type(4))) unsigned short us4;

__device__ __forceinline__ float b2f(bf16 v) { return __bfloat162float(v); }
__device__ __forceinline__ unsigned short f2bf_bits(float f) {
  bf16 h = __float2bfloat16(f);
  return *(unsigned short*)&h;
}
// pack two f32 -> bf16x2 by truncation: one v_perm_b32 (validated round 14)
__device__ __forceinline__ unsigned pkbf_trunc(float lo, float hi) {
  return __builtin_amdgcn_perm(__float_as_uint(hi), __float_as_uint(lo), 0x07060302u);
}
// xor-1 lane exchange via DPP quad_perm [1,0,3,2] (0xB1): VALU, not LDS.
__device__ __forceinline__ float dppx1(float x) {
  return __int_as_float(
      __builtin_amdgcn_mov_dpp(__float_as_int(x), 0xB1, 0xF, 0xF, true));
}
__device__ __forceinline__ int dppx1i(int x) {
  return __builtin_amdgcn_mov_dpp(x, 0xB1, 0xF, 0xF, true);
}

// ---------------------------------------------------------------------------
// K0: weight prep (unchanged).
// ---------------------------------------------------------------------------
__global__ void k_prep(const float* __restrict__ Wo, const float* __restrict__ Wf,
                       const float* __restrict__ Wq,
                       bf16* __restrict__ Wt, bf16* __restrict__ WfT,
                       bf16* __restrict__ WqT) {
  int i = blockIdx.x * 256 + threadIdx.x;
  if (i < 147456) {
    int j = i & 7, lane = (i >> 3) & 63, cot = (i >> 9) & 3;
    int kc = (i >> 11) & 7, r = i >> 14;
    int co = cot * 16 + (lane & 15);
    int ci = kc * 32 + (lane >> 4) * 8 + j;
    Wt[i] = __float2bfloat16(Wo[(co * 256 + ci) * 9 + r]);
  }
  if (i < 4096) {
    int j = i & 7, lane = (i >> 3) & 63, cot = (i >> 9) & 3, kc = (i >> 11) & 1;
    int co = cot * 16 + (lane & 15);
    int ci = kc * 32 + (lane >> 4) * 8 + j;
    WfT[i] = __float2bfloat16(Wf[co * 64 + ci]);
  }
  if (i < 49152) {
    int jj = i & 7, lane = (i >> 3) & 63, g = i >> 9;  // g 0..95
    int nt = g % 48, half = g / 48;
    int ch = half * 32 + (lane >> 4) * 8 + jj;
    int j = nt * 16 + (lane & 15);
    WqT[i] = __float2bfloat16(Wq[ch * 768 + j]);
  }
}

// ---------------------------------------------------------------------------
// K1: qkv projection as MFMA GEMM (round-15: 12-group loop w/ B prefetch).
// ---------------------------------------------------------------------------
__global__ __launch_bounds__(64)
void k_qkv(const float* __restrict__ x, const bf16* __restrict__ WqT,
           const float* __restrict__ bq,
           bf16* __restrict__ q, bf16* __restrict__ k, bf16* __restrict__ vt) {
  __shared__ short xa[16 * 72];  // A-tile [16 l][64 c] (+pad)
  __shared__ short tr[16 * 66];  // transpose buffer for q/k epilogue
  int lane = threadIdx.x;
  int quad = lane >> 4, c = lane & 15;
  int n = blockIdx.x / 100;
  int l0 = (blockIdx.x % 100) * 16;
  bool ev = (c & 1) == 0;

  {
    int l = c;
    const float* xb = x + (size_t)n * 102400 + (size_t)(quad * 16) * 1600 + l0 + l;
    unsigned short vb[16];
#pragma unroll
    for (int i = 0; i < 16; i++) vb[i] = f2bf_bits(xb[(size_t)i * 1600]);
    unsigned wrds[8];
#pragma unroll
    for (int i = 0; i < 8; i++)
      wrds[i] = ((unsigned)vb[2 * i + 1] << 16) | vb[2 * i];
    *(short8*)(xa + l * 72 + quad * 16) = *(short8*)&wrds[0];
    *(short8*)(xa + l * 72 + quad * 16 + 8) = *(short8*)&wrds[4];
  }
  asm volatile("" ::: "memory");
  short8 af0 = *(const short8*)(xa + c * 72 + quad * 8);
  short8 af1 = *(const short8*)(xa + c * 72 + 32 + quad * 8);

  const short* wq0 = (const short*)WqT;
  const float QSCALE = 0.125f * 1.44269504f;

  short8 bc[8], bn[8];
#pragma unroll
  for (int t = 0; t < 4; t++) {
    bc[2 * t]     = *(const short8*)(wq0 + ((size_t)t * 64 + lane) * 8);
    bc[2 * t + 1] = *(const short8*)(wq0 + ((size_t)(48 + t) * 64 + lane) * 8);
  }

#pragma unroll
  for (int g = 0; g < 12; g++) {
    int s = g >> 2, h = g & 3;
    f32x4 z[4];
#pragma unroll
    for (int t = 0; t < 4; t++) {
      int nt = g * 4 + t;
      float bv = bq[nt * 16 + c];
      f32x4 zz = {bv, bv, bv, bv};
      zz = __builtin_amdgcn_mfma_f32_16x16x32_bf16(af0, bc[2 * t], zz, 0, 0, 0);
      zz = __builtin_amdgcn_mfma_f32_16x16x32_bf16(af1, bc[2 * t + 1], zz, 0, 0, 0);
      z[t] = zz;
    }
    if (g < 11) {
#pragma unroll
      for (int t = 0; t < 4; t++) {
        int nt = (g + 1) * 4 + t;
        bn[2 * t]     = *(const short8*)(wq0 + ((size_t)nt * 64 + lane) * 8);
        bn[2 * t + 1] = *(const short8*)(wq0 + ((size_t)(48 + nt) * 64 + lane) * 8);
      }
    }
    if (s < 2) {
      asm volatile("" ::: "memory");
#pragma unroll
      for (int t = 0; t < 4; t++) {
        if (s == 0) {
#pragma unroll
          for (int r = 0; r < 4; r++) z[t][r] *= QSCALE;
        }
        int us_[4];
#pragma unroll
        for (int r = 0; r < 4; r++) us_[r] = f2bf_bits(z[t][r]);
        int xv0 = dppx1i(us_[0]);
        int xv1 = dppx1i(us_[1]);
        int xv2 = dppx1i(us_[2]);
        int xv3 = dppx1i(us_[3]);
        if (ev) {
          *(int*)(tr + (quad * 4 + 0) * 66 + t * 16 + c) = (xv0 << 16) | us_[0];
          *(int*)(tr + (quad * 4 + 1) * 66 + t * 16 + c) = (xv1 << 16) | us_[1];
        } else {
          *(int*)(tr + (quad * 4 + 2) * 66 + t * 16 + (c - 1)) = (us_[2] << 16) | xv2;
          *(int*)(tr + (quad * 4 + 3) * 66 + t * 16 + (c - 1)) = (us_[3] << 16) | xv3;
        }
      }
      asm volatile("" ::: "memory");
      int row = lane >> 2, seg = lane & 3;
      short8 o0 = *(const short8*)(tr + row * 66 + seg * 16);
      short8 o1 = *(const short8*)(tr + row * 66 + seg * 16 + 8);
      short* dstp = (short*)(s == 0 ? q : k);
      short* dst = dstp + ((size_t)(n * 4 + h) * 1600 + l0 + row) * 64 + seg * 16;
      *(short8*)(dst) = o0;
      *(short8*)(dst + 8) = o1;
      asm volatile("" ::: "memory");  // tr reused next group
    } else {
#pragma unroll
      for (int t = 0; t < 4; t++) {
        us4 pk;
#pragma unroll
        for (int r = 0; r < 4; r++) pk[r] = f2bf_bits(z[t][r]);
        *(us4*)((short*)vt + ((size_t)((n * 4 + h) * 64 + t * 16 + c)) * 1600 +
                l0 + quad * 4) = pk;
      }
    }
#pragma unroll
    for (int i = 0; i < 8; i++) bc[i] = bn[i];
  }
}

// ---------------------------------------------------------------------------
// K2: MFMA flash attention, round-16: ONE WAVE PER BLOCK, 64 Q-rows/wave
// (4 accumulating 16-row tiles), ZERO barriers. kbuf (K tile, 9216B) and pl
// (P transpose, 2304B) are wave-private: DS ops are in-order per wave, so
// the 2-barrier staging dance collapses to asm clobbers (k_qkv-proven).
// K staging prefetch (1 iter ahead), V direct loads issued early, fixed-max
// exp2(s-8) folded into MFMA C-init, XCD swizzle, v_perm pack — all kept.
// Loads per kt now feed 72 MFMAs (vs 36): 2x amortization. grid 1600 x 64.
// ---------------------------------------------------------------------------
__global__ __launch_bounds__(64, 2)
void k_attn(const bf16* __restrict__ q, const bf16* __restrict__ k,
            const bf16* __restrict__ vt, bf16* __restrict__ ot) {
  __shared__ short kbuf[64 * 72];  // K tile [64 kv][64 d], padded rows
  __shared__ short pl[1152];       // P transpose: [16 m][72 j], reused per tile
  int lane = threadIdx.x;
  int quad = lane >> 4, c = lane & 15;
  int bid = blockIdx.x;            // 0..1599
  int xcd = bid & 7;
  int slot = bid >> 3;             // 0..199
  int wtile = slot % 25;           // 64-row tile index
  int nh = (slot / 25) * 8 + xcd;  // nh%8 == bid%8 -> per-XCD K/V stream
  int l0 = wtile * 64;             // wave's rows: tiles at l0 + 16*tt

  // Q fragments for 4 tiles
  const short* qbase = (const short*)q + ((size_t)nh * 1600 + l0 + c) * 64 + quad * 8;
  short8 qf[4][2];
#pragma unroll
  for (int tt = 0; tt < 4; tt++) {
    qf[tt][0] = *(const short8*)(qbase + tt * 16 * 64);
    qf[tt][1] = *(const short8*)(qbase + tt * 16 * 64 + 32);
  }

  short ob = (c == 0) ? (short)0x3F80 : (short)0;  // bf16 1.0 in col 0
  short8 onesf = {ob, ob, ob, ob, ob, ob, ob, ob};

  f32x4 acc[4][5] = {};  // per tile: 4 d-tiles + l-tile (ones-trick)

  const short* kg = (const short*)k + (size_t)nh * 102400;
  const short* vg = (const short*)vt + (size_t)nh * 102400;
  bool ev = (c & 1) == 0;
  int cbase = c & ~1;

  // prologue: staging loads for kt=0 (8 x 16B per lane = full 8KB tile)
  short8 sk[8];
  {
    const short8* gk = (const short8*)kg;
#pragma unroll
    for (int i = 0; i < 8; i++) sk[i] = gk[lane + i * 64];
  }

  for (int kt = 0; kt < 25; kt++) {
    // --- write K tile (wave-private, in-order DS; clobbers pin ordering) ---
    asm volatile("" ::: "memory");
#pragma unroll
    for (int i = 0; i < 8; i++) {
      int ch = lane + i * 64;  // chunk: row=ch>>3, off=ch&7
      *(short8*)(kbuf + (ch >> 3) * 72 + (ch & 7) * 8) = sk[i];
    }
    asm volatile("" ::: "memory");
    // --- V frags: issued early, drain under QK+exp2+pack ---
    short8 vf[4][2];
#pragma unroll
    for (int ct = 0; ct < 4; ct++) {
      const short* p0 = vg + (size_t)(ct * 16 + c) * 1600 + kt * 64 + quad * 8;
      vf[ct][0] = *(const short8*)(p0);
      vf[ct][1] = *(const short8*)(p0 + 32);
    }
    if (kt < 24) {  // K staging loads for kt+1; drain during this iteration
      const short8* gk = (const short8*)(kg + (kt + 1) * 4096);
#pragma unroll
      for (int i = 0; i < 8; i++) sk[i] = gk[lane + i * 64];
    }
    // --- K frags from LDS (read once, shared by all 4 tiles) ---
    short8 kf[4][2];
#pragma unroll
    for (int ct = 0; ct < 4; ct++) {
      kf[ct][0] = *(const short8*)(kbuf + (ct * 16 + c) * 72 + quad * 8);
      kf[ct][1] = *(const short8*)(kbuf + (ct * 16 + c) * 72 + 32 + quad * 8);
    }
    // --- per tile: QK (C=-8) -> exp2 -> pack -> pl -> PV ---
#pragma unroll
    for (int tt = 0; tt < 4; tt++) {
      f32x4 s[4];
#pragma unroll
      for (int ct = 0; ct < 4; ct++) {
        f32x4 z = {-8.f, -8.f, -8.f, -8.f};
        z = __builtin_amdgcn_mfma_f32_16x16x32_bf16(qf[tt][0], kf[ct][0], z, 0, 0, 0);
        z = __builtin_amdgcn_mfma_f32_16x16x32_bf16(qf[tt][1], kf[ct][1], z, 0, 0, 0);
        s[ct] = z;
      }
#pragma unroll
      for (int ct = 0; ct < 4; ct++)
#pragma unroll
        for (int r = 0; r < 4; r++) s[ct][r] = exp2f(s[ct][r]);
      asm volatile("" ::: "memory");
#pragma unroll
      for (int ct = 0; ct < 4; ct++) {
        float x0 = dppx1(s[ct][0]);
        float x1 = dppx1(s[ct][1]);
        float x2 = dppx1(s[ct][2]);
        float x3 = dppx1(s[ct][3]);
        float lo0 = ev ? s[ct][0] : x2;
        float hi0 = ev ? x0 : s[ct][2];
        float lo1 = ev ? s[ct][1] : x3;
        float hi1 = ev ? x1 : s[ct][3];
        int r0 = ev ? 0 : 2, r1 = ev ? 1 : 3;
        *(unsigned*)(pl + (quad * 4 + r0) * 72 + ct * 16 + cbase) = pkbf_trunc(lo0, hi0);
        *(unsigned*)(pl + (quad * 4 + r1) * 72 + ct * 16 + cbase) = pkbf_trunc(lo1, hi1);
      }
      asm volatile("" ::: "memory");
      short8 pf0 = *(const short8*)(pl + c * 72 + quad * 8);
      short8 pf1 = *(const short8*)(pl + c * 72 + 32 + quad * 8);
#pragma unroll
      for (int ct = 0; ct < 4; ct++) {
        acc[tt][ct] = __builtin_amdgcn_mfma_f32_16x16x32_bf16(pf0, vf[ct][0], acc[tt][ct], 0, 0, 0);
        acc[tt][ct] = __builtin_amdgcn_mfma_f32_16x16x32_bf16(pf1, vf[ct][1], acc[tt][ct], 0, 0, 0);
      }
      acc[tt][4] = __builtin_amdgcn_mfma_f32_16x16x32_bf16(pf0, onesf, acc[tt][4], 0, 0, 0);
      acc[tt][4] = __builtin_amdgcn_mfma_f32_16x16x32_bf16(pf1, onesf, acc[tt][4], 0, 0, 0);
      asm volatile("" ::: "memory");  // pl reused by next tile
    }
  }
  // --- epilogue per tile: /l, transpose via pl, coalesced stores to ot ---
  int n = nh >> 2, h = nh & 3;
#pragma unroll
  for (int tt = 0; tt < 4; tt++) {
    float linv[4];
#pragma unroll
    for (int r = 0; r < 4; r++)
      linv[r] = 1.0f / __shfl(acc[tt][4][r], lane & 48);  // col-0 lane of quad
    asm volatile("" ::: "memory");
#pragma unroll
    for (int t = 0; t < 4; t++) {
      int us_[4];
#pragma unroll
      for (int r = 0; r < 4; r++) us_[r] = f2bf_bits(acc[tt][t][r] * linv[r]);
      int xv0 = dppx1i(us_[0]);
      int xv1 = dppx1i(us_[1]);
      int xv2 = dppx1i(us_[2]);
      int xv3 = dppx1i(us_[3]);
      if (ev) {
        *(int*)(pl + (quad * 4 + 0) * 66 + t * 16 + c) = (xv0 << 16) | us_[0];
        *(int*)(pl + (quad * 4 + 1) * 66 + t * 16 + c) = (xv1 << 16) | us_[1];
      } else {
        *(int*)(pl + (quad * 4 + 2) * 66 + t * 16 + (c - 1)) = (us_[2] << 16) | xv2;
        *(int*)(pl + (quad * 4 + 3) * 66 + t * 16 + (c - 1)) = (us_[3] << 16) | xv3;
      }
    }
    asm volatile("" ::: "memory");
    int row = lane >> 2, seg = lane & 3;
    short8 o0 = *(const short8*)(pl + row * 66 + seg * 16);
    short8 o1 = *(const short8*)(pl + row * 66 + seg * 16 + 8);
    short* dst = (short*)ot +
                 ((size_t)n * 1600 + l0 + tt * 16 + row) * 256 + h * 64 + seg * 16;
    *(short8*)(dst) = o0;
    *(short8*)(dst + 8) = o1;
    asm volatile("" ::: "memory");  // pl reused by next tile
  }
}

// ---------------------------------------------------------------------------
// K3: fused (1,9)conv+BN1+res+relu -> 1x1conv+BN2+res+relu -> d_out.
// (round-15 fusion, unchanged). grid (50,16), block 128 (2 waves).
// ---------------------------------------------------------------------------
__global__ void k_conv9(const bf16* __restrict__ ot, const bf16* __restrict__ Wt,
                        const float* __restrict__ bo, const float* __restrict__ g1,
                        const float* __restrict__ be1, const float* __restrict__ mu1,
                        const float* __restrict__ va1, const float* __restrict__ x,
                        const bf16* __restrict__ WfT, const float* __restrict__ bff,
                        const float* __restrict__ g2, const float* __restrict__ be2,
                        const float* __restrict__ mu2, const float* __restrict__ va2,
                        float* __restrict__ out) {
  __shared__ short tl[2][16 * 66];
  int wv = threadIdx.x >> 6;
  int lane = threadIdx.x & 63;
  int quad = lane >> 4, c = lane & 15;
  int n = blockIdx.y;
  int l0 = blockIdx.x * 32 + wv * 16;
  int la = l0 + c;
  int va = la % 25;
  const short* obase = (const short*)ot + (size_t)n * 409600;
  const short* wbase = (const short*)Wt;
  f32x4 acc[4] = {};
  for (int r = 0; r < 9; r++) {
    int sh = r - 4;
    bool valid = (unsigned)(va + sh) < 25u;
    int lp = la + sh;
    lp = max(0, min(1599, lp));
    const short* arow = obase + (size_t)lp * 256 + quad * 8;
    const short* wrow = wbase + (size_t)r * 8 * 4 * 64 * 8 + lane * 8;
    short8 z8 = {0, 0, 0, 0, 0, 0, 0, 0};
#pragma unroll 4
    for (int kc = 0; kc < 8; kc++) {
      short8 af = *(const short8*)(arow + kc * 32);
      af = valid ? af : z8;
      const short* wk = wrow + kc * 4 * 64 * 8;
      short8 b0 = *(const short8*)(wk);
      short8 b1 = *(const short8*)(wk + 512);
      short8 b2 = *(const short8*)(wk + 1024);
      short8 b3 = *(const short8*)(wk + 1536);
      acc[0] = __builtin_amdgcn_mfma_f32_16x16x32_bf16(af, b0, acc[0], 0, 0, 0);
      acc[1] = __builtin_amdgcn_mfma_f32_16x16x32_bf16(af, b1, acc[1], 0, 0, 0);
      acc[2] = __builtin_amdgcn_mfma_f32_16x16x32_bf16(af, b2, acc[2], 0, 0, 0);
      acc[3] = __builtin_amdgcn_mfma_f32_16x16x32_bf16(af, b3, acc[3], 0, 0, 0);
    }
  }
  short* tlw = &tl[wv][0];
  float outv[4][4];
#pragma unroll
  for (int cot = 0; cot < 4; cot++) {
    int co = cot * 16 + c;
    float inv = g1[co] * rsqrtf(va1[co] + 1e-5f);
    float add = be1[co] - mu1[co] * inv + bo[co] * inv;
    f32x4 xr = *(const f32x4*)(x + (size_t)(n * 64 + co) * 1600 + l0 + quad * 4);
#pragma unroll
    for (int rr = 0; rr < 4; rr++)
      outv[cot][rr] = fmaxf(acc[cot][rr] * inv + add + xr[rr], 0.f);
  }
  asm volatile("" ::: "memory");
  bool ev = (c & 1) == 0;
#pragma unroll
  for (int cot = 0; cot < 4; cot++) {
    int us_[4];
#pragma unroll
    for (int rr = 0; rr < 4; rr++) us_[rr] = f2bf_bits(outv[cot][rr]);
    int xv0 = dppx1i(us_[0]);
    int xv1 = dppx1i(us_[1]);
    int xv2 = dppx1i(us_[2]);
    int xv3 = dppx1i(us_[3]);
    if (ev) {
      *(int*)(tlw + (quad * 4 + 0) * 66 + cot * 16 + c) = (xv0 << 16) | us_[0];
      *(int*)(tlw + (quad * 4 + 1) * 66 + cot * 16 + c) = (xv1 << 16) | us_[1];
    } else {
      *(int*)(tlw + (quad * 4 + 2) * 66 + cot * 16 + (c - 1)) = (us_[2] << 16) | xv2;
      *(int*)(tlw + (quad * 4 + 3) * 66 + cot * 16 + (c - 1)) = (us_[3] << 16) | xv3;
    }
  }
  asm volatile("" ::: "memory");
  short8 afY0 = *(const short8*)(tlw + c * 66 + quad * 8);
  short8 afY1 = *(const short8*)(tlw + c * 66 + 32 + quad * 8);
  const short* wfb = (const short*)WfT + lane * 8;
  f32x4 acc2[4] = {};
#pragma unroll
  for (int kc = 0; kc < 2; kc++) {
    short8 afk = kc ? afY1 : afY0;
    const short* wk = wfb + kc * 2048;
    short8 b0 = *(const short8*)(wk);
    short8 b1 = *(const short8*)(wk + 512);
    short8 b2 = *(const short8*)(wk + 1024);
    short8 b3 = *(const short8*)(wk + 1536);
    acc2[0] = __builtin_amdgcn_mfma_f32_16x16x32_bf16(afk, b0, acc2[0], 0, 0, 0);
    acc2[1] = __builtin_amdgcn_mfma_f32_16x16x32_bf16(afk, b1, acc2[1], 0, 0, 0);
    acc2[2] = __builtin_amdgcn_mfma_f32_16x16x32_bf16(afk, b2, acc2[2], 0, 0, 0);
    acc2[3] = __builtin_amdgcn_mfma_f32_16x16x32_bf16(afk, b3, acc2[3], 0, 0, 0);
  }
#pragma unroll
  for (int cot = 0; cot < 4; cot++) {
    int co = cot * 16 + c;
    float inv = g2[co] * rsqrtf(va2[co] + 1e-5f);
    float add = be2[co] - mu2[co] * inv + bff[co] * inv;
    f32x4 ov;
#pragma unroll
    for (int rr = 0; rr < 4; rr++)
      ov[rr] = fmaxf(acc2[cot][rr] * inv + add + outv[cot][rr], 0.f);
    *(f32x4*)(out + (size_t)(n * 64 + co) * 1600 + l0 + quad * 4) = ov;
  }
}

extern "C" void kernel_launch(void* const* d_in, const int* in_sizes, int n_in,
                              void* d_out, int out_size, void* d_ws, size_t ws_size,
                              hipStream_t stream) {
  const float* x   = (const float*)d_in[0];
  const float* Wq  = (const float*)d_in[1];
  const float* bq  = (const float*)d_in[2];
  const float* Wo  = (const float*)d_in[3];
  const float* bo  = (const float*)d_in[4];
  const float* g1  = (const float*)d_in[5];
  const float* be1 = (const float*)d_in[6];
  const float* mu1 = (const float*)d_in[7];
  const float* va1 = (const float*)d_in[8];
  const float* Wf  = (const float*)d_in[9];
  const float* bff = (const float*)d_in[10];
  const float* g2  = (const float*)d_in[11];
  const float* be2 = (const float*)d_in[12];
  const float* mu2 = (const float*)d_in[13];
  const float* va2 = (const float*)d_in[14];

  // ws (bf16 elems): q,k [nh][l][64]; vt [nh][64][l]; ot [n][l][256];
  //                  Wt; WfT; WqT   (~52.8 MB)
  const size_t QKV = (size_t)64 * 1600 * 64;
  bf16* qw  = (bf16*)d_ws;
  bf16* kw  = qw + QKV;
  bf16* vtw = kw + QKV;
  bf16* otw = vtw + QKV;
  bf16* Wt  = otw + QKV;
  bf16* WfT = Wt + 147456;
  bf16* WqT = WfT + 4096;

  k_prep<<<576, 256, 0, stream>>>(Wo, Wf, Wq, Wt, WfT, WqT);
  k_qkv<<<1600, 64, 0, stream>>>(x, WqT, bq, qw, kw, vtw);
  k_attn<<<1600, 64, 0, stream>>>(qw, kw, vtw, otw);
  dim3 gc(50, 16);
  k_conv9<<<gc, 128, 0, stream>>>(otw, Wt, bo, g1, be1, mu1, va1, x,
                                  WfT, bff, g2, be2, mu2, va2, (float*)d_out);
}